// Round 10
// baseline (412.023 us; speedup 1.0000x reference)
//
#include <hip/hip_runtime.h>
#include <hip/hip_bf16.h>
#include <stdint.h>

typedef unsigned int uint;
typedef unsigned long long ull;

#define NPRE   6000
#define NPOST  1000
#define NW     94          // 64-bit words covering 6016 rows
#define NSR    47          // super-rounds of 2 words
#define MCAP   16384
#define IMG_W  1216.0f
#define IMG_H  800.0f

// ---------- workspace layout (bytes) ----------
#define WS_KEYS    0            // uint[2M]           8,000,000
#define WS_HIST    8000000      // uint[256]
#define WS_STATE   8001024      // uint[16]           [1]=M
#define WS_K64     8001088      // ull[MCAP]
#define WS_IDX     8132160      // int[MCAP]
#define WS_SORTED  8263232      // float4[6016]
#define WS_MASK    8359488      // ull[6016*94]       4,524,032

__device__ __forceinline__ float exp_ref(float x) { return (float)exp((double)x); }

__device__ __forceinline__ float sigmoid_ref(float x) {
#pragma clang fp contract(off)
    float e = exp_ref(-x);
    float d = 1.0f + e;
    return 1.0f / d;
}

__device__ __forceinline__ bool decode_box(float4 a, float4 d,
                                           float& x1, float& y1, float& x2, float& y2) {
#pragma clang fp contract(off)
    float wa = a.z - a.x;
    float ha = a.w - a.y;
    float xa = a.x + 0.5f * wa;
    float ya = a.y + 0.5f * ha;
    float x  = d.x * wa + xa;
    float y  = d.y * ha + ya;
    float w  = exp_ref(d.z) * wa;
    float h  = exp_ref(d.w) * ha;
    x1 = fminf(fmaxf(x - 0.5f * w, 0.0f), IMG_W - 1.0f);
    y1 = fminf(fmaxf(y - 0.5f * h, 0.0f), IMG_H - 1.0f);
    x2 = fminf(fmaxf(x + 0.5f * w, 0.0f), IMG_W - 1.0f);
    y2 = fminf(fmaxf(y + 0.5f * h, 0.0f), IMG_H - 1.0f);
    return (x2 - x1 >= 16.0f) && (y2 - y1 >= 16.0f);
}

// suppress candidate b by picked a? reference: iou = inter/((area_a+area_b)-inter); !(iou<=0.7)
__device__ __forceinline__ bool sup_check(float ax1, float ay1, float ax2, float ay2, float aar,
                                          float bx1, float by1, float bx2, float by2, float bar) {
#pragma clang fp contract(off)
    float xx1 = fmaxf(ax1, bx1);
    float yy1 = fmaxf(ay1, by1);
    float xx2 = fminf(ax2, bx2);
    float yy2 = fminf(ay2, by2);
    float inter = fmaxf(xx2 - xx1, 0.0f) * fmaxf(yy2 - yy1, 0.0f);
    float uni = (aar + bar) - inter;
    return !(inter / uni <= 0.7f);
}

// decode validity + sigmoid key; LDS 256-bin hist of key bits[23:16] for keys with top byte 0xBF
__global__ void k_decode_hist(const float4* __restrict__ A, const float4* __restrict__ D,
                              const float* __restrict__ L, uint* __restrict__ keys,
                              uint* __restrict__ hist, int N) {
    __shared__ uint h[256];
    int t = threadIdx.x;
    h[t] = 0;
    __syncthreads();
    for (int i = blockIdx.x * blockDim.x + t; i < N; i += gridDim.x * blockDim.x) {
        float x1, y1, x2, y2;
        bool ok = decode_box(A[i], D[i], x1, y1, x2, y2);
        uint key = 0u;
        if (ok) {
            float s = sigmoid_ref(L[i]);
            key = __float_as_uint(s) | 0x80000000u;
        }
        keys[i] = key;
        if ((key >> 24) == 0xBFu) atomicAdd(&h[(key >> 16) & 0xFFu], 1u);
    }
    __syncthreads();
    uint v = h[t];
    if (v) atomicAdd(&hist[t], v);
}

// wave-0 shuffle suffix-scan of hist -> T16; select keys >= T16; wave-agg push
__global__ __launch_bounds__(256) void k_compact16(const uint* __restrict__ keys, int N,
                                                   const uint* __restrict__ hist, uint* state,
                                                   ull* __restrict__ K64, int* __restrict__ idxArr) {
    __shared__ uint t8s;
    int t = threadIdx.x;
    if (t == 0) t8s = 0;
    __syncthreads();
    if (t < 64) {
        uint b0 = hist[4 * t], b1 = hist[4 * t + 1], b2 = hist[4 * t + 2], b3 = hist[4 * t + 3];
        uint s = b0 + b1 + b2 + b3;
        uint v = s;
        for (int off = 1; off < 64; off <<= 1) {
            uint u = (uint)__shfl_down((int)v, off, 64);
            if (t + off < 64) v += u;
        }
        uint eh = v - s;                    // sum over lanes > t
        uint S3 = eh + b3, S2 = S3 + b2, S1 = S2 + b1, S0 = S1 + b0;
        int t8 = -1;
        if (S0 >= NPRE && S1 < NPRE) t8 = 4 * t;
        if (S1 >= NPRE && S2 < NPRE) t8 = 4 * t + 1;
        if (S2 >= NPRE && S3 < NPRE) t8 = 4 * t + 2;
        if (S3 >= NPRE && eh < NPRE) t8 = 4 * t + 3;
        if (t8 >= 0) t8s = (uint)t8;
    }
    __syncthreads();
    uint T16 = 0xBF00u | t8s;

    int i = blockIdx.x * blockDim.x + t;
    int lane = t & 63;
    uint key = (i < N) ? keys[i] : 0u;
    bool push = (i < N) && ((key >> 16) >= T16);
    ull b = __ballot(push);
    if (!b) return;
    int ldr = __builtin_ctzll(b);
    uint base = 0;
    if (lane == ldr) base = atomicAdd(&state[1], (uint)__builtin_popcountll(b));
    base = (uint)__shfl((int)base, ldr, 64);
    if (push) {
        uint p = base + (uint)__builtin_popcountll(b & ((1ull << lane) - 1ull));
        if (p < MCAP) {
            K64[p] = ((ull)key << 32) | (uint)(~(uint)i);  // score desc, idx asc
            idxArr[p] = i;
        }
    }
}

// fused rank + scatter: each block ranks its 256 candidates against all M, then scatters
__global__ __launch_bounds__(256) void k_rankscatter(const ull* __restrict__ K64,
                                                     const uint* __restrict__ state,
                                                     const int* __restrict__ idxArr,
                                                     const float4* __restrict__ A,
                                                     const float4* __restrict__ D,
                                                     float4* __restrict__ sorted) {
    __shared__ ull tile[256];
    int M = (int)min(state[1], (uint)MCAP);
    if ((int)blockIdx.x * 256 >= M) return;
    int i = blockIdx.x * 256 + threadIdx.x;
    ull mine = (i < M) ? K64[i] : 0ull;
    uint cnt = 0;
    for (int base = 0; base < M; base += 256) {
        int j = base + threadIdx.x;
        tile[threadIdx.x] = (j < M) ? K64[j] : 0ull;
        __syncthreads();
        int lim = min(256, M - base);
        for (int t = 0; t < lim; ++t) cnt += (tile[t] > mine);
        __syncthreads();
    }
    if (i < M && cnt < NPRE) {
        int idx = idxArr[i];
        float x1, y1, x2, y2;
        decode_box(A[idx], D[idx], x1, y1, x2, y2);
        sorted[cnt] = make_float4(x1, y1, x2, y2);
    }
}

// strict-upper-triangle suppression mask: mask[row][cw] for cw > row/64
__global__ __launch_bounds__(64) void k_mask(const float4* __restrict__ sorted,
                                             ull* __restrict__ mask) {
#pragma clang fp contract(off)
    if (blockIdx.x <= blockIdx.y) return;
    __shared__ float4 cb[64];
    __shared__ float  ca[64];
    int cw = blockIdx.x, rc = blockIdx.y, t = threadIdx.x;
    float4 b = sorted[cw * 64 + t];
    cb[t] = b;
    ca[t] = (b.z - b.x) * (b.w - b.y);
    __syncthreads();
    int row = rc * 64 + t;
    float4 rb = sorted[row];
    float  ra = (rb.z - rb.x) * (rb.w - rb.y);
    ull bits = 0;
    for (int j = 0; j < 64; ++j)
        if (sup_check(rb.x, rb.y, rb.z, rb.w, ra,
                      cb[j].x, cb[j].y, cb[j].z, cb[j].w, ca[j]))
            bits |= 1ull << j;
    mask[(size_t)row * NW + cw] = bits;
}

// greedy NMS, super-rounds of 2 words: per barrier-pair wave0 picks word 2s,
// VALU-fresh-applies its picks to word 2s+1, then picks word 2s+1.
// Lag loads (prev SR's picks onto words [2s,NW)) as in R5; plain __syncthreads.
__global__ __launch_bounds__(1024) void k_nms(const float4* __restrict__ sorted,
                                              const ull* __restrict__ mask,
                                              float* __restrict__ out) {
    int tid = threadIdx.x, lane = tid & 63, w = tid >> 6;   // 16 waves
    __shared__ float kx1[NPOST], ky1[NPOST], kx2[NPOST], ky2[NPOST];
    __shared__ int   fIdx[128];
    __shared__ float cbx1[4][64], cby1[4][64], cbx2[4][64], cby2[4][64], cbar[4][64];
    __shared__ ull   intra[128];
    __shared__ uint  remLo[NW], remHi[NW];
    __shared__ int   kcS, nfS;

    for (int i = tid; i < NW; i += 1024) { remLo[i] = 0; remHi[i] = 0; }
    if (tid < 256) {   // preload words 0..3 into bufs 0..3
#pragma clang fp contract(off)
        float4 b = sorted[tid];
        int bf = tid >> 6;
        cbx1[bf][lane] = b.x; cby1[bf][lane] = b.y;
        cbx2[bf][lane] = b.z; cby2[bf][lane] = b.w;
        cbar[bf][lane] = (b.z - b.x) * (b.w - b.y);
    }
    float4 nb = make_float4(0.f, 0.f, 0.f, 0.f);
    if (w >= 14) {     // regs for words 4,5
        int ld = 4 + (w - 14);
        if (ld < NW) nb = sorted[ld * 64 + lane];
    }
    if (tid == 0) { kcS = 0; nfS = 0; }
    __syncthreads();

    int kc = 0, nf = 0;
    for (int s = 0; s < NSR; ++s) {
        int wA = 2 * s, wB = 2 * s + 1;
        int bufA = wA & 3, bufB = wB & 3;
        // ---- phase A (16 waves) ----
        // (1) lag loads first (maximize overlap before barrier drain):
        //     prev SR's picks onto words [wA, NW)
        {
            int nwf = NW - wA;
            int pairs = nf * nwf;
            for (int p = tid; p < pairs; p += 1024) {
                int k = p / nwf, ww = wA + (p - k * nwf);
                ull m = mask[(size_t)fIdx[k] * NW + ww];
                uint lo = (uint)m, hi = (uint)(m >> 32);
                if (lo) atomicOr(&remLo[ww], lo);
                if (hi) atomicOr(&remHi[ww], hi);
            }
        }
        // (2) prefetch: write words 2s+2,2s+3 from regs (loaded last SR); load 2s+4,2s+5
        if (w >= 14) {
#pragma clang fp contract(off)
            if (s >= 1) {
                int wd = 2 * s + 2 + (w - 14);
                if (wd < NW) {
                    int bf = wd & 3;
                    cbx1[bf][lane] = nb.x; cby1[bf][lane] = nb.y;
                    cbx2[bf][lane] = nb.z; cby2[bf][lane] = nb.w;
                    cbar[bf][lane] = (nb.z - nb.x) * (nb.w - nb.y);
                }
            }
            int ld = 2 * s + 4 + (w - 14);
            if (ld < NW) nb = sorted[ld * 64 + lane];
        }
        // (3) intra ballots: 128 rows over 16 waves; waves 0-7 word A, 8-15 word B
        {
            int mybuf = (w < 8) ? bufA : bufB;
            float cx1 = cbx1[mybuf][lane], cy1 = cby1[mybuf][lane];
            float cx2 = cbx2[mybuf][lane], cy2 = cby2[mybuf][lane], car = cbar[mybuf][lane];
            for (int i2 = 0; i2 < 8; ++i2) {
                int r = w * 8 + i2;              // 0..127
                int rr = r & 63;
                bool sup = sup_check(cbx1[mybuf][rr], cby1[mybuf][rr], cbx2[mybuf][rr],
                                     cby2[mybuf][rr], cbar[mybuf][rr],
                                     cx1, cy1, cx2, cy2, car);
                ull bal = __ballot(sup);
                if (lane == 0) intra[r] = bal;
            }
        }
        __syncthreads();
        // ---- phase B (wave 0): pick word A, fresh-apply, pick word B ----
        if (w == 0) {
            float cAx1 = cbx1[bufA][lane], cAy1 = cby1[bufA][lane];
            float cAx2 = cbx2[bufA][lane], cAy2 = cby2[bufA][lane], cAar = cbar[bufA][lane];
            float cBx1 = cbx1[bufB][lane], cBy1 = cby1[bufB][lane];
            float cBx2 = cbx2[bufB][lane], cBy2 = cby2[bufB][lane], cBar = cbar[bufB][lane];
            ull rowA = intra[lane];
            ull rowB = intra[64 + lane];
            uint rAlo = (uint)rowA, rAhi = (uint)(rowA >> 32);
            uint rBlo = (uint)rowB, rBhi = (uint)(rowB >> 32);
            int kcl = kc;
            // word A pick
            ull aliveA = ~(((ull)remHi[wA] << 32) | (ull)remLo[wA]);
            ull keptA = 0;
            while (aliveA && kcl < NPOST) {
                int j = __builtin_ctzll(aliveA);
                int js = __builtin_amdgcn_readfirstlane(j);
                keptA |= 1ull << js;
                kcl++;
                uint mlo = __builtin_amdgcn_readlane(rAlo, js);
                uint mhi = __builtin_amdgcn_readlane(rAhi, js);
                aliveA &= ~(((ull)mhi << 32) | (ull)mlo);
                aliveA &= ~(1ull << js);
            }
            // fresh-apply picks(A) to word B cols
            ull fB = 0;
            {
                ull kb = keptA;
                while (kb) {
                    int j = __builtin_ctzll(kb);
                    int js = __builtin_amdgcn_readfirstlane(j);
                    kb &= kb - 1;
                    float px1 = __builtin_amdgcn_readlane(__float_as_uint(cAx1), js) ? 0.f : 0.f;
                    // readlane on float via uint bits:
                    uint u1 = __builtin_amdgcn_readlane(__float_as_uint(cAx1), js);
                    uint u2 = __builtin_amdgcn_readlane(__float_as_uint(cAy1), js);
                    uint u3 = __builtin_amdgcn_readlane(__float_as_uint(cAx2), js);
                    uint u4 = __builtin_amdgcn_readlane(__float_as_uint(cAy2), js);
                    uint u5 = __builtin_amdgcn_readlane(__float_as_uint(cAar), js);
                    (void)px1;
                    bool sup = sup_check(__uint_as_float(u1), __uint_as_float(u2),
                                         __uint_as_float(u3), __uint_as_float(u4),
                                         __uint_as_float(u5),
                                         cBx1, cBy1, cBx2, cBy2, cBar);
                    fB |= __ballot(sup);
                }
            }
            // word B pick
            ull rmB = (((ull)remHi[wB] << 32) | (ull)remLo[wB]) | fB;
            if (wB == NW - 1) rmB |= 0xFFFF000000000000ull;   // rows 6000..6015 invalid
            ull aliveB = ~rmB;
            ull keptB = 0;
            while (aliveB && kcl < NPOST) {
                int j = __builtin_ctzll(aliveB);
                int js = __builtin_amdgcn_readfirstlane(j);
                keptB |= 1ull << js;
                kcl++;
                uint mlo = __builtin_amdgcn_readlane(rBlo, js);
                uint mhi = __builtin_amdgcn_readlane(rBhi, js);
                aliveB &= ~(((ull)mhi << 32) | (ull)mlo);
                aliveB &= ~(1ull << js);
            }
            // self-copy kept boxes (A picks first, then B — score order)
            int nA = __builtin_popcountll(keptA);
            if ((keptA >> lane) & 1ull) {
                int r = kc + __builtin_popcountll(keptA & ((1ull << lane) - 1ull));
                kx1[r] = cAx1; ky1[r] = cAy1; kx2[r] = cAx2; ky2[r] = cAy2;
                fIdx[r - kc] = wA * 64 + lane;
            }
            if ((keptB >> lane) & 1ull) {
                int r = kc + nA + __builtin_popcountll(keptB & ((1ull << lane) - 1ull));
                kx1[r] = cBx1; ky1[r] = cBy1; kx2[r] = cBx2; ky2[r] = cBy2;
                fIdx[r - kc] = wB * 64 + lane;
            }
            if (lane == 0) { kcS = kcl; nfS = kcl - kc; }
        }
        __syncthreads();
        kc = kcS; nf = nfS;
        if (kc >= NPOST) break;
    }
    float4* o4 = (float4*)out;
    for (int r = tid; r < NPOST; r += 1024) {
        float4 b = make_float4(0.f, 0.f, 0.f, 0.f);
        if (r < kc) b = make_float4(kx1[r], ky1[r], kx2[r], ky2[r]);
        o4[r] = b;
    }
}

extern "C" void kernel_launch(void* const* d_in, const int* in_sizes, int n_in,
                              void* d_out, int out_size, void* d_ws, size_t ws_size,
                              hipStream_t stream) {
    const float4* A = (const float4*)d_in[2];   // anchors (N,4)
    const float4* D = (const float4*)d_in[3];   // bbox_deltas (N,4)
    const float*  L = (const float*)d_in[4];    // logits (N,1)
    int N = in_sizes[4];

    char* ws = (char*)d_ws;
    uint*   keys   = (uint*)(ws + WS_KEYS);
    uint*   hist   = (uint*)(ws + WS_HIST);
    uint*   state  = (uint*)(ws + WS_STATE);
    ull*    K64    = (ull*)(ws + WS_K64);
    int*    idxArr = (int*)(ws + WS_IDX);
    float4* sorted = (float4*)(ws + WS_SORTED);
    ull*    mask   = (ull*)(ws + WS_MASK);
    float*  out    = (float*)d_out;

    int nblk = (N + 255) / 256;

    hipMemsetAsync(ws + WS_HIST, 0, 1088, stream);   // hist[256] + state[16]
    k_decode_hist<<<2048, 256, 0, stream>>>(A, D, L, keys, hist, N);
    k_compact16<<<nblk, 256, 0, stream>>>(keys, N, hist, state, K64, idxArr);
    k_rankscatter<<<64, 256, 0, stream>>>(K64, state, idxArr, A, D, sorted);
    k_mask<<<dim3(NW, NW), 64, 0, stream>>>(sorted, mask);
    k_nms<<<1, 1024, 0, stream>>>(sorted, mask, out);
}

// Round 11
// 272.703 us; speedup vs baseline: 1.5109x; 1.5109x over previous
//
#include <hip/hip_runtime.h>
#include <hip/hip_bf16.h>
#include <stdint.h>

typedef unsigned int uint;
typedef unsigned long long ull;

#define NPRE   6000
#define NPOST  1000
#define NW     94          // ceil(6016/64)
#define MCAP   16384
#define IMG_W  1216.0f
#define IMG_H  800.0f

// ---------- workspace layout (bytes) ----------
#define WS_KEYS    0            // uint[2M]           8,000,000
#define WS_HIST    8000000      // uint[256]
#define WS_STATE   8001024      // uint[16]           [0]=t8, [1]=M
#define WS_K64     8001088      // ull[MCAP]
#define WS_IDX     8132160      // int[MCAP]
#define WS_RANK    8197696      // uint[MCAP]
#define WS_SORTED  8263232      // float4[6016]
#define WS_MASK    8359488      // ull[6016*94]       4,524,032

__device__ __forceinline__ float exp_ref(float x) { return (float)exp((double)x); }

__device__ __forceinline__ float sigmoid_ref(float x) {
#pragma clang fp contract(off)
    float e = exp_ref(-x);
    float d = 1.0f + e;
    return 1.0f / d;
}

__device__ __forceinline__ bool decode_box(float4 a, float4 d,
                                           float& x1, float& y1, float& x2, float& y2) {
#pragma clang fp contract(off)
    float wa = a.z - a.x;
    float ha = a.w - a.y;
    float xa = a.x + 0.5f * wa;
    float ya = a.y + 0.5f * ha;
    float x  = d.x * wa + xa;
    float y  = d.y * ha + ya;
    float w  = exp_ref(d.z) * wa;
    float h  = exp_ref(d.w) * ha;
    x1 = fminf(fmaxf(x - 0.5f * w, 0.0f), IMG_W - 1.0f);
    y1 = fminf(fmaxf(y - 0.5f * h, 0.0f), IMG_H - 1.0f);
    x2 = fminf(fmaxf(x + 0.5f * w, 0.0f), IMG_W - 1.0f);
    y2 = fminf(fmaxf(y + 0.5f * h, 0.0f), IMG_H - 1.0f);
    return (x2 - x1 >= 16.0f) && (y2 - y1 >= 16.0f);
}

// suppress candidate b by picked a? reference: iou = inter/((area_a+area_b)-inter); !(iou<=0.7)
__device__ __forceinline__ bool sup_check(float ax1, float ay1, float ax2, float ay2, float aar,
                                          float bx1, float by1, float bx2, float by2, float bar) {
#pragma clang fp contract(off)
    float xx1 = fmaxf(ax1, bx1);
    float yy1 = fmaxf(ay1, by1);
    float xx2 = fminf(ax2, bx2);
    float yy2 = fminf(ay2, by2);
    float inter = fmaxf(xx2 - xx1, 0.0f) * fmaxf(yy2 - yy1, 0.0f);
    float uni = (aar + bar) - inter;
    return !(inter / uni <= 0.7f);
}

__global__ void k_init(uint* hist, uint* state, uint* rank, float4* sorted) {
    int t = blockIdx.x * blockDim.x + threadIdx.x;
    for (int i = t; i < MCAP; i += gridDim.x * blockDim.x) rank[i] = 0;
    if (t < 256) hist[t] = 0;
    if (t < 16)  state[t] = 0;
    if (t < 16)  sorted[NPRE + t] = make_float4(0.f, 0.f, 0.f, 0.f);
}

// decode validity + sigmoid key; LDS 256-bin hist of key bits[23:16] for keys with top byte 0xBF
__global__ void k_decode_hist(const float4* __restrict__ A, const float4* __restrict__ D,
                              const float* __restrict__ L, uint* __restrict__ keys,
                              uint* __restrict__ hist, int N) {
    __shared__ uint h[256];
    int t = threadIdx.x;
    h[t] = 0;
    __syncthreads();
    for (int i = blockIdx.x * blockDim.x + t; i < N; i += gridDim.x * blockDim.x) {
        float x1, y1, x2, y2;
        bool ok = decode_box(A[i], D[i], x1, y1, x2, y2);
        uint key = 0u;
        if (ok) {
            float s = sigmoid_ref(L[i]);
            key = __float_as_uint(s) | 0x80000000u;
        }
        keys[i] = key;
        if ((key >> 24) == 0xBFu) atomicAdd(&h[(key >> 16) & 0xFFu], 1u);
    }
    __syncthreads();
    uint v = h[t];
    if (v) atomicAdd(&hist[t], v);
}

// per-block suffix scan of hist -> T16; select all keys >= T16; wave-aggregated push
__global__ __launch_bounds__(256) void k_compact16(const uint* __restrict__ keys, int N,
                                                   const uint* __restrict__ hist, uint* state,
                                                   ull* __restrict__ K64, int* __restrict__ idxArr) {
    __shared__ uint S[256];
    __shared__ uint t8s;
    int t = threadIdx.x;
    if (t == 0) t8s = 0;
    S[t] = hist[t];
    __syncthreads();
    for (int off = 1; off < 256; off <<= 1) {
        uint v = S[t] + ((t + off < 256) ? S[t + off] : 0u);
        __syncthreads();
        S[t] = v;
        __syncthreads();
    }
    uint Sincl = S[t];
    uint Sexcl = (t < 255) ? S[t + 1] : 0u;
    if (Sincl >= NPRE && Sexcl < NPRE) t8s = (uint)t;
    __syncthreads();
    uint T16 = 0xBF00u | t8s;

    int i = blockIdx.x * blockDim.x + t;
    int lane = t & 63;
    uint key = (i < N) ? keys[i] : 0u;
    bool push = (i < N) && ((key >> 16) >= T16);
    ull b = __ballot(push);
    if (!b) return;
    int ldr = __builtin_ctzll(b);
    uint base = 0;
    if (lane == ldr) base = atomicAdd(&state[1], (uint)__builtin_popcountll(b));
    base = (uint)__shfl((int)base, ldr, 64);
    if (push) {
        uint p = base + (uint)__builtin_popcountll(b & ((1ull << lane) - 1ull));
        if (p < MCAP) {
            K64[p] = ((ull)key << 32) | (uint)(~(uint)i);  // score desc, idx asc
            idxArr[p] = i;
        }
    }
}

// partial ranks: grid (64 row-blocks x 8 col-slices); rank[i] += #{j in slice: K64[j] > K64[i]}
__global__ __launch_bounds__(256) void k_rank(const ull* __restrict__ K64,
                                              const uint* __restrict__ state,
                                              uint* __restrict__ rank) {
    __shared__ ull tile[256];
    int M = (int)min(state[1], (uint)MCAP);
    if ((int)blockIdx.x * 256 >= M) return;
    int i = blockIdx.x * 256 + threadIdx.x;
    int W = (M + 7) / 8;
    int c0 = blockIdx.y * W;
    int c1 = min(c0 + W, M);
    ull mine = (i < M) ? K64[i] : 0ull;
    uint cnt = 0;
    for (int base = c0; base < c1; base += 256) {
        int j = base + threadIdx.x;
        tile[threadIdx.x] = (j < c1) ? K64[j] : 0ull;
        __syncthreads();
        int lim = min(256, c1 - base);
        for (int t = 0; t < lim; ++t) cnt += (tile[t] > mine);
        __syncthreads();
    }
    if (i < M && cnt) atomicAdd(&rank[i], cnt);
}

// candidates with rank < NPRE: decode box, write to sorted[rank]
__global__ void k_scatter(const float4* __restrict__ A, const float4* __restrict__ D,
                          const uint* __restrict__ state, const uint* __restrict__ rank,
                          const int* __restrict__ idxArr, float4* __restrict__ sorted) {
    int i = blockIdx.x * blockDim.x + threadIdx.x;
    int M = (int)min(state[1], (uint)MCAP);
    if (i >= M) return;
    uint r = rank[i];
    if (r >= NPRE) return;
    int idx = idxArr[i];
    float x1, y1, x2, y2;
    decode_box(A[idx], D[idx], x1, y1, x2, y2);
    sorted[r] = make_float4(x1, y1, x2, y2);
}

// strict-upper-triangle suppression mask: mask[row][cw] for cw > row/64
__global__ __launch_bounds__(64) void k_mask(const float4* __restrict__ sorted,
                                             ull* __restrict__ mask) {
#pragma clang fp contract(off)
    if (blockIdx.x <= blockIdx.y) return;
    __shared__ float4 cb[64];
    __shared__ float  ca[64];
    int cw = blockIdx.x, rc = blockIdx.y, t = threadIdx.x;
    float4 b = sorted[cw * 64 + t];
    cb[t] = b;
    ca[t] = (b.z - b.x) * (b.w - b.y);
    __syncthreads();
    int row = rc * 64 + t;
    float4 rb = sorted[row];
    float  ra = (rb.z - rb.x) * (rb.w - rb.y);
    ull bits = 0;
    for (int j = 0; j < 64; ++j)
        if (sup_check(rb.x, rb.y, rb.z, rb.w, ra,
                      cb[j].x, cb[j].y, cb[j].z, cb[j].w, ca[j]))
            bits |= 1ull << j;
    mask[(size_t)row * NW + cw] = bits;
}

// greedy NMS (R5 structure): intra-chunk via on-the-fly ballots; previous chunk's fresh
// picks applied to rem words [c, NW) via parallel global mask loads issued at the TOP of
// phase A (max overlap before the barrier's vmcnt drain), ready at the phase-A barrier.
__global__ __launch_bounds__(1024) void k_nms(const float4* __restrict__ sorted,
                                              const ull* __restrict__ mask,
                                              float* __restrict__ out) {
    int tid = threadIdx.x, lane = tid & 63, w = tid >> 6;
    __shared__ float kx1[NPOST], ky1[NPOST], kx2[NPOST], ky2[NPOST];
    __shared__ int   fIdx[64];
    __shared__ float cbx1[2][64], cby1[2][64], cbx2[2][64], cby2[2][64], cbar[2][64];
    __shared__ ull   intra[64];
    __shared__ uint  remLo[NW], remHi[NW];
    __shared__ int   kcS, nfS;

    for (int i = tid; i < NW; i += 1024) { remLo[i] = 0; remHi[i] = 0; }
    if (tid < 64) {
#pragma clang fp contract(off)
        float4 b = sorted[tid];
        cbx1[0][tid] = b.x; cby1[0][tid] = b.y; cbx2[0][tid] = b.z; cby2[0][tid] = b.w;
        cbar[0][tid] = (b.z - b.x) * (b.w - b.y);
    }
    if (tid == 0) { kcS = 0; nfS = 0; }
    __syncthreads();

    int kc = 0, nf = 0;
    for (int c = 0; c < NW; ++c) {
        int cur = c & 1;
        // ---- phase A (all waves) ----
        // (1) lag loads FIRST: fresh picks of chunk c-1 onto words [c, NW)
        int nw2 = NW - c;
        int pairs = nf * nw2;
        for (int p = tid; p < pairs; p += 1024) {
            int k  = p / nw2;
            int ww = c + (p - k * nw2);
            ull m = mask[(size_t)fIdx[k] * NW + ww];
            uint lo = (uint)m, hi = (uint)(m >> 32);
            if (lo) atomicOr(&remLo[ww], lo);
            if (hi) atomicOr(&remHi[ww], hi);
        }
        // (2) next-chunk prefetch (w15)
        bool pf = (w == 15) && (c + 1 < NW);
        float4 nb;
        if (pf) nb = sorted[(c + 1) * 64 + lane];
        // (3) intra-chunk mask rows 4w..4w+3 via ballot
        float cx1 = cbx1[cur][lane], cy1 = cby1[cur][lane];
        float cx2 = cbx2[cur][lane], cy2 = cby2[cur][lane], car = cbar[cur][lane];
        for (int i2 = 0; i2 < 4; ++i2) {
            int r = w * 4 + i2;
            bool sup = sup_check(cbx1[cur][r], cby1[cur][r], cbx2[cur][r], cby2[cur][r],
                                 cbar[cur][r], cx1, cy1, cx2, cy2, car);
            ull bal = __ballot(sup);
            if (lane == 0) intra[r] = bal;
        }
        if (pf) {
#pragma clang fp contract(off)
            int nxt = cur ^ 1;
            cbx1[nxt][lane] = nb.x; cby1[nxt][lane] = nb.y;
            cbx2[nxt][lane] = nb.z; cby2[nxt][lane] = nb.w;
            cbar[nxt][lane] = (nb.z - nb.x) * (nb.w - nb.y);
        }
        __syncthreads();   // drains lag loads -> rem[c] complete
        // ---- phase B (wave 0) ----
        if (w == 0) {
            ull myrow = intra[lane];
            ull rm = ((ull)remHi[c] << 32) | (ull)remLo[c];
            if (c == NW - 1) rm |= 0xFFFF000000000000ull;  // rows 6000..6015 invalid
            ull alive = ~rm;
            uint rlo = (uint)myrow, rhi = (uint)(myrow >> 32);
            ull keptbits = 0;
            int kcl = kc;
            while (alive && kcl < NPOST) {
                int j = __builtin_ctzll(alive);
                int js = __builtin_amdgcn_readfirstlane(j);   // ensure SGPR lane index
                keptbits |= 1ull << js;
                kcl++;
                uint mlo = __builtin_amdgcn_readlane(rlo, js);
                uint mhi = __builtin_amdgcn_readlane(rhi, js);
                alive &= ~(((ull)mhi << 32) | (ull)mlo);
                alive &= ~(1ull << js);
            }
            if ((keptbits >> lane) & 1ull) {   // kept col: self-copy
                int r = kc + __builtin_popcountll(keptbits & ((1ull << lane) - 1ull));
                kx1[r] = cx1; ky1[r] = cy1; kx2[r] = cx2; ky2[r] = cy2;
                fIdx[r - kc] = c * 64 + lane;
            }
            if (lane == 0) { kcS = kcl; nfS = kcl - kc; }
        }
        __syncthreads();
        kc = kcS; nf = nfS;
        if (kc >= NPOST) break;
    }
    float4* o4 = (float4*)out;
    for (int r = tid; r < NPOST; r += 1024) {
        float4 b = make_float4(0.f, 0.f, 0.f, 0.f);
        if (r < kc) b = make_float4(kx1[r], ky1[r], kx2[r], ky2[r]);
        o4[r] = b;
    }
}

extern "C" void kernel_launch(void* const* d_in, const int* in_sizes, int n_in,
                              void* d_out, int out_size, void* d_ws, size_t ws_size,
                              hipStream_t stream) {
    const float4* A = (const float4*)d_in[2];   // anchors (N,4)
    const float4* D = (const float4*)d_in[3];   // bbox_deltas (N,4)
    const float*  L = (const float*)d_in[4];    // logits (N,1)
    int N = in_sizes[4];

    char* ws = (char*)d_ws;
    uint*   keys   = (uint*)(ws + WS_KEYS);
    uint*   hist   = (uint*)(ws + WS_HIST);
    uint*   state  = (uint*)(ws + WS_STATE);
    ull*    K64    = (ull*)(ws + WS_K64);
    int*    idxArr = (int*)(ws + WS_IDX);
    uint*   rank   = (uint*)(ws + WS_RANK);
    float4* sorted = (float4*)(ws + WS_SORTED);
    ull*    mask   = (ull*)(ws + WS_MASK);
    float*  out    = (float*)d_out;

    int nblk = (N + 255) / 256;

    k_init<<<16, 1024, 0, stream>>>(hist, state, rank, sorted);
    k_decode_hist<<<2048, 256, 0, stream>>>(A, D, L, keys, hist, N);
    k_compact16<<<nblk, 256, 0, stream>>>(keys, N, hist, state, K64, idxArr);
    k_rank<<<dim3(64, 8), 256, 0, stream>>>(K64, state, rank);
    k_scatter<<<64, 256, 0, stream>>>(A, D, state, rank, idxArr, sorted);
    k_mask<<<dim3(NW, NW), 64, 0, stream>>>(sorted, mask);
    k_nms<<<1, 1024, 0, stream>>>(sorted, mask, out);
}